// Round 16
// baseline (88816.479 us; speedup 1.0000x reference)
//
#include <hip/hip_runtime.h>
#include <hip/hip_cooperative_groups.h>

namespace cg = cooperative_groups;

#define Bb   256   // batch
#define Tt   512   // time steps
#define INx  19    // input features
#define Hh   512   // hidden
#define NWG  256   // (unit-group 0..127 of 4 units) x (batch-half 0..1 of 128)
#define NTHR 512   // 8 waves = (su 0..3) x (bh 0..1); lane = (kq 0..3) x (bg 0..15)

#define WROWS 48                      // 4 units x 12 rows
#define WSTR  528                     // proven bank-safe stride
#define WLDS_FLOATS (WROWS * WSTR)    // 101376 B
#define WX1_FLOATS  (16 * 20)
#define FCB_FLOATS  (Hh + 256 + 128)
#define SMEM_FLOATS (WLDS_FLOATS + WX1_FLOATS + FCB_FLOATS)
#define SMEM_BYTES  (SMEM_FLOATS * 4)

typedef unsigned int u32;
typedef unsigned long long u64;

__device__ __forceinline__ float sigf(float x) { return 1.0f / (1.0f + __expf(-x)); }
__device__ __forceinline__ float tanhfast(float x) {
    float e = __expf(2.0f * x);
    return 1.0f - 2.0f / (e + 1.0f);
}

union pcast { u64 u; float2 f; };
// h path is FULLY uncached (LLC-direct both ways): stores agent-relaxed,
// loads agent-relaxed -> always fresh, NO acquire fence ever needed.
// Weights live in LDS; x / FC weights are read-only -> L1/L2 never invalidated.
__device__ __forceinline__ void gstore2(float2* p, float2 v) {
    pcast c; c.f = v;
    __hip_atomic_store((u64*)p, c.u, __ATOMIC_RELAXED, __HIP_MEMORY_SCOPE_AGENT);
}
__device__ __forceinline__ float2 gload2(const float2* p) {
    pcast c;
    c.u = __hip_atomic_load((const u64*)p, __ATOMIC_RELAXED, __HIP_MEMORY_SCOPE_AGENT);
    return c.f;
}

// Counter barrier: tid0 arrives (release RMW orders the WG's drained h stores),
// tid0 ALONE polls the single counter line (1 LLC load/round vs 65K with the
// flag array), syncthreads releases the other waves. No cache maintenance.
__device__ __forceinline__ void cbar(u32* ctr, int tid, u32 phase) {
    __syncthreads();   // all waves' h stores drained (vmcnt) before arrival
    if (tid == 0) {
        __hip_atomic_fetch_add(ctr, 1u, __ATOMIC_RELEASE, __HIP_MEMORY_SCOPE_AGENT);
        const u32 target = phase * (u32)NWG;
        while (__hip_atomic_load(ctr, __ATOMIC_RELAXED, __HIP_MEMORY_SCOPE_AGENT) < target)
            __builtin_amdgcn_s_sleep(2);
    }
    __syncthreads();   // release: h of all WGs is at LLC, loads go LLC-direct
}

// load chunk c: 4 consecutive k's x 4 batches of (h1,h2) pairs, 16 x 8B atomic
__device__ __forceinline__ void ldchunk(const float2* __restrict__ hp, int c,
                                        float2 (&H)[4][4]) {
    #pragma unroll
    for (int kk = 0; kk < 4; ++kk)
        #pragma unroll
        for (int b = 0; b < 4; ++b)
            H[kk][b] = gload2(hp + (size_t)(c * 4 + kk) * Bb + b);
}

// 192 FMA per chunk: 12 weight rows (LDS broadcast) x 4 k x 4 batches.
// a2 merges W2x·h1 + W2h·h2 (proven r9/r15).
__device__ __forceinline__ void fmac(const float2 (&H)[4][4],
                                     const float* __restrict__ wk,
                                     float (&a1)[4][4], float (&a2)[4][4]) {
    #pragma unroll
    for (int g = 0; g < 4; ++g) {
        const float4 w1 = *reinterpret_cast<const float4*>(wk + (0 + g) * WSTR);
        const float4 w2 = *reinterpret_cast<const float4*>(wk + (4 + g) * WSTR);
        const float4 w3 = *reinterpret_cast<const float4*>(wk + (8 + g) * WSTR);
        #pragma unroll
        for (int b = 0; b < 4; ++b) {
            a1[g][b] += H[0][b].x*w1.x + H[1][b].x*w1.y + H[2][b].x*w1.z + H[3][b].x*w1.w;
            a2[g][b] += H[0][b].x*w2.x + H[1][b].x*w2.y + H[2][b].x*w2.z + H[3][b].x*w2.w
                      + H[0][b].y*w3.x + H[1][b].y*w3.y + H[2][b].y*w3.z + H[3][b].y*w3.w;
        }
    }
}

// per-thread constant (not compile-time) index -> cndmask chain, no scratch
__device__ __forceinline__ float sel4(const float (&a)[4], int k) {
    float v = a[0];
    v = (k == 1) ? a[1] : v;
    v = (k == 2) ? a[2] : v;
    v = (k == 3) ? a[3] : v;
    return v;
}

__global__ void __launch_bounds__(NTHR, 2)
lstm_fused(const float* __restrict__ input,
           const float* __restrict__ l1_Wx, const float* __restrict__ l1_bx,
           const float* __restrict__ l1_Wh, const float* __restrict__ l1_bh,
           const float* __restrict__ l2_Wx, const float* __restrict__ l2_bx,
           const float* __restrict__ l2_Wh, const float* __restrict__ l2_bh,
           const float* __restrict__ fc1_W, const float* __restrict__ fc1_b,
           const float* __restrict__ fc2_W, const float* __restrict__ fc2_b,
           const float* __restrict__ fc3_W, const float* __restrict__ fc3_b,
           float* __restrict__ out, float* __restrict__ ws)
{
    extern __shared__ float smem[];
    float* wlds = smem;                      // [48 rows][528] weights
    float* wx1l = smem + WLDS_FLOATS;        // [4u][4g][20]
    float* fcb  = wx1l + WX1_FLOATS;

    cg::grid_group grid = cg::this_grid();
    const int wgid = blockIdx.x;
    const int ug = wgid >> 1;        // unit-group
    const int bs = wgid & 1;         // batch-half
    const int jb = ug * 4;           // first owned unit
    const int tid = threadIdx.x;

    const int wid = __builtin_amdgcn_readfirstlane(tid >> 6);
    const int su = wid & 3;          // unit within group (wave-uniform)
    const int bh = wid >> 2;         // batch block of 64 (wave-uniform)
    const int lane = tid & 63;
    const int kq = lane >> 4;        // K quarter
    const int bg = lane & 15;
    const int bB = bs * 128 + bh * 64 + bg * 4;   // lane's 4-batch block
    const int bfin = bB + kq;        // the ONE batch this lane finishes/owns
    const int j  = jb + su;          // owned unit

    float2* PA = (float2*)ws;        // P[j][b] = (h1[t], h2[t-1])
    float2* PB = PA + (size_t)Hh * Bb;
    u32* ctr = (u32*)(PB + (size_t)Hh * Bb);

    if (wgid == 0 && tid == 0)
        __hip_atomic_store(ctr, 0u, __ATOMIC_RELAXED, __HIP_MEMORY_SCOPE_AGENT);
    grid.sync();   // fences ctr reset; the only runtime cg sync

    // ---- stage 4 units x 12 rows of weights into LDS (once) ----
    for (int idx = tid; idx < WROWS * Hh; idx += NTHR) {
        const int row = idx >> 9, k = idx & 511;
        const int u = row / 12, rr = row - u * 12;
        const int m = rr >> 2, g = rr & 3;
        const float* src = (m == 0) ? l1_Wh : (m == 1) ? l2_Wx : l2_Wh;
        wlds[row * WSTR + (k >> 7) * 132 + (k & 127)] =
            src[(size_t)(g * Hh + jb + u) * Hh + k];
    }
    if (tid < 16 * INx) {
        const int r = tid / INx, i = tid - r * INx;
        const int u = r >> 2, g = r & 3;
        wx1l[r * 20 + i] = l1_Wx[(size_t)(g * Hh + jb + u) * INx + i];
    }
    float b1r[4], b2r[4];
    #pragma unroll
    for (int g = 0; g < 4; ++g) {
        const int row = g * Hh + j;
        b1r[g] = l1_bx[row] + l1_bh[row];
        b2r[g] = l2_bx[row] + l2_bh[row];
    }
    __syncthreads();

    const float* wlane = wlds + (su * 12) * WSTR + kq * 132;

    // ---- prologue: every lane computes h1[0] for ITS batch bfin ----
    float c1 = 0.f, c2 = 0.f;
    {
        const float* xr = input + (size_t)bfin * Tt * INx;
        float s[4];
        #pragma unroll
        for (int g = 0; g < 4; ++g) {
            float acc = b1r[g];
            #pragma unroll
            for (int i = 0; i < INx; ++i) acc += xr[i] * wx1l[(su * 4 + g) * 20 + i];
            s[g] = acc;
        }
        c1 = sigf(s[0]) * tanhfast(s[2]);      // f*0 + i*g
        gstore2(&PA[(size_t)j * Bb + bfin],
                make_float2(sigf(s[3]) * tanhfast(c1), 0.f));
    }
    cbar(ctr, tid, 1u);

    const float2* Pc = PA; float2* Pn = PB;

    for (int t = 0; t < Tt; ++t) {
        const bool doL1 = (t < Tt - 1);

        float a1[4][4], a2[4][4];
        #pragma unroll
        for (int g = 0; g < 4; ++g)
            #pragma unroll
            for (int b = 0; b < 4; ++b) { a1[g][b] = 0.f; a2[g][b] = 0.f; }

        // lane pair base: element (k, b) at Pc[(kq*128 + k)*Bb + bB + b]
        const float2* hp = Pc + (size_t)(kq * 128) * Bb + bB;

        // double-buffered pipeline over 32 chunks of 4 k's (LLC-direct loads)
        float2 HA[4][4], HB[4][4];
        ldchunk(hp, 0, HA);
        #pragma unroll 1
        for (int c = 0; c < 32; c += 2) {
            ldchunk(hp, c + 1, HB);
            fmac(HA, wlane + (c    ) * 4, a1, a2);
            if (c < 30) ldchunk(hp, c + 2, HA);
            fmac(HB, wlane + (c + 1) * 4, a1, a2);
        }

        // ---- butterfly K-reduce over the 4 kq groups (lane bits 4,5) ----
        #pragma unroll
        for (int g = 0; g < 4; ++g) {
            #pragma unroll
            for (int b = 0; b < 4; ++b) {
                float v = a1[g][b]; v += __shfl_xor(v, 16, 64); v += __shfl_xor(v, 32, 64); a1[g][b] = v;
                float w = a2[g][b]; w += __shfl_xor(w, 16, 64); w += __shfl_xor(w, 32, 64); a2[g][b] = w;
            }
        }

        // ---- finish: ALL lanes active; lane handles batch bfin ----
        {
            float h1v = 0.f;
            if (doL1) {
                const float* xr = input + ((size_t)bfin * Tt + t + 1) * INx;   // cached, hot
                float s1[4];
                #pragma unroll
                for (int g = 0; g < 4; ++g) {
                    float acc = sel4(a1[g], kq) + b1r[g];
                    #pragma unroll
                    for (int i = 0; i < INx; ++i) acc += xr[i] * wx1l[(su * 4 + g) * 20 + i];
                    s1[g] = acc;
                }
                const float ig = sigf(s1[0]), fg = sigf(s1[1]);
                const float gg = tanhfast(s1[2]), og = sigf(s1[3]);
                c1 = fg * c1 + ig * gg;
                h1v = og * tanhfast(c1);
            }
            const float ig = sigf(sel4(a2[0], kq) + b2r[0]);
            const float fg = sigf(sel4(a2[1], kq) + b2r[1]);
            const float gg = tanhfast(sel4(a2[2], kq) + b2r[2]);
            const float og = sigf(sel4(a2[3], kq) + b2r[3]);
            c2 = fg * c2 + ig * gg;
            gstore2(&Pn[(size_t)j * Bb + bfin], make_float2(h1v, og * tanhfast(c2)));
        }

        cbar(ctr, tid, (u32)(t + 2));

        const float2* tp = Pc; Pc = Pn; Pn = (float2*)tp;
    }
    // final h2 = Pc[.].y (visible: LLC-direct reads after last cbar)

    // ---------- FC head: WG wgid handles batch wgid ----------
    float* hh  = fcb;
    float* a1s = fcb + Hh;
    float* a2s = fcb + Hh + 256;
    hh[tid] = gload2(&Pc[(size_t)tid * Bb + wgid]).y;
    __syncthreads();
    if (tid < 256) {
        float acc = fc1_b[tid];
        const float* wr = fc1_W + (size_t)tid * Hh;
        for (int i = 0; i < Hh; ++i) acc += wr[i] * hh[i];
        a1s[tid] = fmaxf(acc, 0.0f);
    }
    __syncthreads();
    if (tid < 128) {
        float acc = fc2_b[tid];
        const float* wr = fc2_W + (size_t)tid * 256;
        for (int i = 0; i < 256; ++i) acc += wr[i] * a1s[i];
        a2s[tid] = fmaxf(acc, 0.0f);
    }
    __syncthreads();
    if (tid == 0) {
        float acc = fc3_b[0];
        for (int i = 0; i < 128; ++i) acc += fc3_W[i] * a2s[i];
        out[wgid] = acc;
    }
}

extern "C" void kernel_launch(void* const* d_in, const int* in_sizes, int n_in,
                              void* d_out, int out_size, void* d_ws, size_t ws_size,
                              hipStream_t stream)
{
    (void)in_sizes; (void)n_in; (void)out_size; (void)ws_size;

    const float* input = (const float*)d_in[0];
    const float* l1_Wx = (const float*)d_in[1];
    const float* l1_bx = (const float*)d_in[2];
    const float* l1_Wh = (const float*)d_in[3];
    const float* l1_bh = (const float*)d_in[4];
    const float* l2_Wx = (const float*)d_in[5];
    const float* l2_bx = (const float*)d_in[6];
    const float* l2_Wh = (const float*)d_in[7];
    const float* l2_bh = (const float*)d_in[8];
    const float* fc1_W = (const float*)d_in[9];
    const float* fc1_b = (const float*)d_in[10];
    const float* fc2_W = (const float*)d_in[11];
    const float* fc2_b = (const float*)d_in[12];
    const float* fc3_W = (const float*)d_in[13];
    const float* fc3_b = (const float*)d_in[14];
    float* out = (float*)d_out;
    float* ws  = (float*)d_ws;

    hipFuncSetAttribute((const void*)lstm_fused,
                        hipFuncAttributeMaxDynamicSharedMemorySize, SMEM_BYTES);

    void* args[] = {
        &input,
        &l1_Wx, &l1_bx, &l1_Wh, &l1_bh,
        &l2_Wx, &l2_bx, &l2_Wh, &l2_bh,
        &fc1_W, &fc1_b, &fc2_W, &fc2_b, &fc3_W, &fc3_b,
        &out, &ws
    };
    hipLaunchCooperativeKernel((void*)lstm_fused, dim3(NWG), dim3(NTHR), args,
                               SMEM_BYTES, stream);
}